// Round 22
// baseline (152.736 us; speedup 1.0000x reference)
//
#include <hip/hip_runtime.h>
#include <hip/hip_bf16.h>

#define DD 256
#define NROWS 16384
#define NBLK 256  // == CU count; 1 block/CU; all co-resident (spin-safe)

typedef float f32x4 __attribute__((ext_vector_type(4)));
typedef __bf16 bf16x4 __attribute__((ext_vector_type(4)));
typedef __bf16 bf16x8 __attribute__((ext_vector_type(8)));

__device__ __forceinline__ bf16x8 cvt8(f32x4 lo, f32x4 hi) {
  bf16x8 v;
#pragma unroll
  for (int j = 0; j < 4; ++j) {
    v[j] = (__bf16)lo[j];
    v[4 + j] = (__bf16)hi[j];
  }
  return v;
}

// ---------------------------------------------------------------------------
// ONE dispatch, producer-consumer (R9 redesigned; failure modes fixed):
//  - each block PRODUCES one Wc row (bid) + bc[bid]: work spread over all
//    256 CUs, overlapped with its own x staging loads (issued first);
//  - Wc/bc written via device-scope atomicExch (cross-XCD coherent; R9-
//    validated correctness), release = threadfence + barrier (vmcnt drain);
//  - completion counter: ONE atomicAdd per block; lane-0-only RELAXED atomic
//    LOAD polling + s_sleep (R9 used 512 RMW pollers -- the 165us mistake);
//  - grid 256 x 1024thr, 36KB LDS, VGPR<=128 -> 1 block/CU, all resident;
//  - consume phase = R21-validated K2 (wave owns 16 cols, af[8]=32 VGPR,
//    one barrier, LDS bf16 residual, D-layout col=l&15 row=g4*4+reg),
//    64 rows/block, nontemporal out stores (out never re-read).
// Counter zeroed per replay by a 4B hipMemsetAsync node (graph-capturable).
// ---------------------------------------------------------------------------
__global__ __launch_bounds__(1024, 4) void fused_knn(
    const float* __restrict__ x, const float* __restrict__ Wqkv,
    const float* __restrict__ bqkv, const float* __restrict__ Wout,
    const float* __restrict__ bout, __bf16* __restrict__ Wc,
    float* __restrict__ bc, unsigned int* __restrict__ ctr,
    float* __restrict__ out) {
  __shared__ __bf16 xs[64 * DD];   // 32 KiB x tile (bf16, swizzled)
  __shared__ float prod[4][DD];    // 4 KiB producer partials
  __shared__ float red[4];

  const int t = threadIdx.x;
  const int w = t >> 6, l = t & 63;  // 16 waves
  const int bid = blockIdx.x;
  const int Rbase = bid * 64;
  const float* __restrict__ Wv = Wqkv + 2 * DD * DD;
  const float* __restrict__ bv = bqkv + 2 * DD;

  // ---- Stage x tile (64 rows): issued FIRST so HBM latency overlaps the
  // production phase below.
  {
    const int sr = t >> 4, sc = t & 15;
    const int ssw = (sr & 7) << 4;
    const int sbase = sr * 512 + sc * 32;
    const float* s0 = x + (size_t)(Rbase + sr) * DD + sc * 16;
    f32x4 a = *(const f32x4*)(s0 + 0);
    f32x4 b = *(const f32x4*)(s0 + 4);
    f32x4 c = *(const f32x4*)(s0 + 8);
    f32x4 d = *(const f32x4*)(s0 + 12);
    *(bf16x8*)((char*)xs + ((sbase + 0) ^ ssw)) = cvt8(a, b);
    *(bf16x8*)((char*)xs + ((sbase + 16) ^ ssw)) = cvt8(c, d);
  }

  // ---- Produce Wc row 'bid': thread (j = t&255, dg = t>>8) accumulates
  // 64 d's; Wv loads coalesced (wave spans 64 consecutive j).
  {
    const int j = t & 255, dg = t >> 8;
    const float* wvp = Wv + (size_t)(dg * 64) * DD + j;
    const float* wo = Wout + (size_t)bid * DD + dg * 64;
    float acc = 0.f;
#pragma unroll 8
    for (int dd = 0; dd < 64; ++dd) acc += wo[dd] * wvp[(size_t)dd * DD];
    prod[dg][j] = acc;
  }
  if (t < 256) {  // bc partial (waves 0-3)
    float p = Wout[(size_t)bid * DD + t] * bv[t];
#pragma unroll
    for (int off = 32; off > 0; off >>= 1) p += __shfl_down(p, off);
    if ((t & 63) == 0) red[t >> 6] = p;
  }
  __syncthreads();
  if (t < 128) {  // pack 2 bf16, device-scope write to coherence point
    const float s0 = prod[0][2 * t] + prod[1][2 * t] + prod[2][2 * t] + prod[3][2 * t];
    const float s1 = prod[0][2 * t + 1] + prod[1][2 * t + 1] + prod[2][2 * t + 1] + prod[3][2 * t + 1];
    const unsigned short u0 = __builtin_bit_cast(unsigned short, (__bf16)s0);
    const unsigned short u1 = __builtin_bit_cast(unsigned short, (__bf16)s1);
    atomicExch((unsigned int*)((char*)Wc + ((size_t)bid * DD + 2 * t) * 2),
               (unsigned int)u0 | ((unsigned int)u1 << 16));
  }
  if (t == 0)
    atomicExch((unsigned int*)(bc + bid),
               __builtin_bit_cast(unsigned int,
                                  bout[bid] + red[0] + red[1] + red[2] + red[3]));

  __threadfence();  // release our Wc/bc writes
  __syncthreads();  // barrier drains the block's outstanding atomics (vmcnt 0)
  if (t == 0) {
    atomicAdd(ctr, 1u);  // signal row done
    while (__hip_atomic_load(ctr, __ATOMIC_RELAXED, __HIP_MEMORY_SCOPE_AGENT) <
           NBLK)
      __builtin_amdgcn_s_sleep(8);  // read-only poll, lane 0 only
  }
  __syncthreads();
  __threadfence();  // acquire: fresh Wc/bc reads below

  // ---- Consume (R21-validated K2): wave w owns out-cols [16w,+16).
  const int xrow = l & 15, g4 = l >> 4;
  const int C0 = w * 16;
  bf16x8 af[8];
  {
    const __bf16* wrp = Wc + (size_t)(C0 + xrow) * DD + g4 * 8;
#pragma unroll
    for (int ks = 0; ks < 8; ++ks) af[ks] = *(const bf16x8*)(wrp + ks * 32);
  }
  const f32x4 bias = *(const f32x4*)(bc + C0 + g4 * 4);  // incl. bout

#pragma unroll
  for (int rt = 0; rt < 4; ++rt) {  // four 16-row tiles (64 rows/block)
    const int lrow = rt * 16 + xrow;
    const int lsw = (lrow & 7) << 4;
    bf16x8 xf[8];
#pragma unroll
    for (int ks = 0; ks < 8; ++ks)
      xf[ks] = *(const bf16x8*)((const char*)xs +
                                ((lrow * 512 + ks * 64 + g4 * 16) ^ lsw));
    f32x4 acc = {0.f, 0.f, 0.f, 0.f};
#pragma unroll
    for (int ks = 0; ks < 8; ++ks)
      acc = __builtin_amdgcn_mfma_f32_16x16x32_bf16(af[ks], xf[ks], acc, 0, 0, 0);
    // D: col(l&15)=x-row, rowquad g4*4+reg = out-col (verified R5..R21).
    const int ocol = C0 + g4 * 4;
    bf16x4 xr4 = *(const bf16x4*)((const char*)xs +
                                  ((lrow * 512 + ocol * 2) ^ lsw));
    f32x4 xres;
#pragma unroll
    for (int j = 0; j < 4; ++j) xres[j] = (float)xr4[j];
    f32x4 o = acc + xres + bias;
    // out is never re-read: nontemporal store keeps L2 for Wc/x.
    __builtin_nontemporal_store(o, (f32x4*)(out + (size_t)(Rbase + lrow) * DD + ocol));
  }
}

extern "C" void kernel_launch(void* const* d_in, const int* in_sizes, int n_in,
                              void* d_out, int out_size, void* d_ws, size_t ws_size,
                              hipStream_t stream) {
  const float* x = (const float*)d_in[0];
  const float* Wqkv = (const float*)d_in[1];
  const float* bqkv = (const float*)d_in[2];
  const float* Wout = (const float*)d_in[3];
  const float* bout = (const float*)d_in[4];
  float* out = (float*)d_out;

  __bf16* Wc = (__bf16*)d_ws;                                    // 128 KiB
  float* bc = (float*)((char*)d_ws + DD * DD * sizeof(__bf16));  // +1 KiB
  unsigned int* ctr = (unsigned int*)((char*)d_ws + 132 * 1024);

  hipMemsetAsync(ctr, 0, sizeof(unsigned int), stream);  // per-replay reset
  fused_knn<<<NBLK, 1024, 0, stream>>>(x, Wqkv, bqkv, Wout, bout, Wc, bc, ctr,
                                       out);
}

// Round 24
// 20.180 us; speedup vs baseline: 7.5687x; 7.5687x over previous
//
#include <hip/hip_runtime.h>
#include <hip/hip_bf16.h>

#define DD 256
#define NROWS 16384

typedef float f32x4 __attribute__((ext_vector_type(4)));
typedef __bf16 bf16x4 __attribute__((ext_vector_type(4)));
typedef __bf16 bf16x8 __attribute__((ext_vector_type(8)));

__device__ __forceinline__ bf16x8 cvt8(f32x4 lo, f32x4 hi) {
  bf16x8 v;
#pragma unroll
  for (int j = 0; j < 4; ++j) {
    v[j] = (__bf16)lo[j];
    v[4 + j] = (__bf16)hi[j];
  }
  return v;
}

// ---------------------------------------------------------------------------
// K1: Wc = Wout @ Wv (bf16), bc = bout + Wout @ bv.  [R19 version VERBATIM]
// ---------------------------------------------------------------------------
__global__ __launch_bounds__(1024) void wc_bc_kernel(
    const float* __restrict__ Wqkv, const float* __restrict__ bqkv,
    const float* __restrict__ Wout, const float* __restrict__ bout,
    __bf16* __restrict__ Wc, float* __restrict__ bc) {
  __shared__ float part[16][4][64];  // 16 KiB
  __shared__ float red[4];
  const int b = blockIdx.x;
  const int i0 = (b >> 2) * 4;
  const int qc = b & 3;
  const int c0 = qc * 64;
  const int t = threadIdx.x;
  const int w = t >> 6, l = t & 63;
  const float* __restrict__ Wv = Wqkv + 2 * DD * DD;
  const float* __restrict__ bv = bqkv + 2 * DD;

  float wo[4][16];
#pragma unroll
  for (int r = 0; r < 4; ++r)
#pragma unroll
    for (int jj = 0; jj < 16; ++jj)
      wo[r][jj] = Wout[(size_t)(i0 + r) * DD + w * 16 + jj];

  float acc0 = 0.f, acc1 = 0.f, acc2 = 0.f, acc3 = 0.f;
  const float* wvp = Wv + (size_t)(w * 16) * DD + c0 + l;
#pragma unroll
  for (int jj = 0; jj < 16; ++jj) {
    const float wv = wvp[(size_t)jj * DD];
    acc0 += wo[0][jj] * wv;
    acc1 += wo[1][jj] * wv;
    acc2 += wo[2][jj] * wv;
    acc3 += wo[3][jj] * wv;
  }
  part[w][0][l] = acc0;
  part[w][1][l] = acc1;
  part[w][2][l] = acc2;
  part[w][3][l] = acc3;

  if (qc == 0 && t < 256) {
    const int r = t >> 6, ll = t & 63;
    float p = 0.f;
#pragma unroll
    for (int k = 0; k < 4; ++k)
      p += Wout[(size_t)(i0 + r) * DD + k * 64 + ll] * bv[k * 64 + ll];
#pragma unroll
    for (int off = 32; off > 0; off >>= 1) p += __shfl_down(p, off);
    if (ll == 0) red[r] = p;
  }
  __syncthreads();
  if (t < 256) {
    const int r = t >> 6, ll = t & 63;
    float s = 0.f;
#pragma unroll
    for (int k = 0; k < 16; ++k) s += part[k][r][ll];
    Wc[(size_t)(i0 + r) * DD + c0 + ll] = (__bf16)s;
    if (qc == 0 && ll == 0) bc[i0 + r] = bout[i0 + r] + red[r];
  }
}

// ---------------------------------------------------------------------------
// K2: out = x + x @ Wc^T + bc.  [R21 body + coalesced-store epilogue;
// R23's bug fixed: LDS physical byte (l*16)^rsw holds LOGICAL column l*16,
// so the global store goes to column l*4 (contiguous full-row wave store),
// not to the permuted offset.]
// ---------------------------------------------------------------------------
__global__ __launch_bounds__(1024, 2) void knn_attn_main(
    const float* __restrict__ x, const __bf16* __restrict__ Wc,
    const float* __restrict__ bc, float* __restrict__ out) {
  __shared__ __bf16 xs[32 * DD];  // 16 KiB x tile, swizzled
  __shared__ float osd[32 * DD];  // 32 KiB output staging, swizzled

  const int t = threadIdx.x;
  const int w = t >> 6, l = t & 63;  // 16 waves
  const int Rbase = blockIdx.x * 32;
  const int xrow = l & 15, g4 = l >> 4;
  const int C0 = w * 16;  // this wave's 16 out-cols

  // Weight fragments (32 VGPR) + bias, issued before staging barrier.
  bf16x8 af[8];
  {
    const __bf16* wrp = Wc + (size_t)(C0 + xrow) * DD + g4 * 8;
#pragma unroll
    for (int ks = 0; ks < 8; ++ks) af[ks] = *(const bf16x8*)(wrp + ks * 32);
  }
  const f32x4 bias = *(const f32x4*)(bc + C0 + g4 * 4);  // incl. bout

  // Stage 32 rows: 1024 thr -> row sr = t>>5, 8 floats at seg sc = t&31.
  {
    const int sr = t >> 5, sc = t & 31;
    const int ssw = (sr & 7) << 4;
    const float* s0 = x + (size_t)(Rbase + sr) * DD + sc * 8;
    f32x4 a = *(const f32x4*)(s0);
    f32x4 b = *(const f32x4*)(s0 + 4);
    *(bf16x8*)((char*)xs + ((sr * 512 + sc * 16) ^ ssw)) = cvt8(a, b);
  }
  __syncthreads();

  // Compute both 16-row tiles; results to swizzled osd.
#pragma unroll
  for (int rt = 0; rt < 2; ++rt) {
    const int lrow = rt * 16 + xrow;
    const int lsw = (lrow & 7) << 4;
    bf16x8 xf[8];
#pragma unroll
    for (int ks = 0; ks < 8; ++ks)
      xf[ks] = *(const bf16x8*)((const char*)xs +
                                ((lrow * 512 + ks * 64 + g4 * 16) ^ lsw));
    f32x4 acc = {0.f, 0.f, 0.f, 0.f};
#pragma unroll
    for (int ks = 0; ks < 8; ++ks)
      acc = __builtin_amdgcn_mfma_f32_16x16x32_bf16(af[ks], xf[ks], acc, 0, 0, 0);
    // D: col(l&15)=x-row, rowquad g4*4+reg = out-col (verified R5..R21).
    const int ocol = C0 + g4 * 4;
    bf16x4 xr4 = *(const bf16x4*)((const char*)xs +
                                  ((lrow * 512 + ocol * 2) ^ lsw));
    f32x4 xres;
#pragma unroll
    for (int j = 0; j < 4; ++j) xres[j] = (float)xr4[j];
    f32x4 o = acc + xres + bias;
    // physical = logical(ocol*4) ^ lsw within the 1KB row
    *(f32x4*)((char*)osd + (lrow * 1024 + ((ocol * 4) ^ lsw))) = o;
  }
  __syncthreads();

  // Store pass: wave w stores rows {w, 16+w}. Lane l reads LDS physical
  // byte (l*16)^rsw, which holds LOGICAL column bytes l*16 -> store at
  // column l*4: one full contiguous 1KB row per wave instruction.
#pragma unroll
  for (int rt = 0; rt < 2; ++rt) {
    const int r = rt * 16 + w;
    const int cbp = (l * 16) ^ ((r & 7) << 4);  // physical LDS byte in row
    f32x4 o = *(const f32x4*)((const char*)osd + (r * 1024 + cbp));
    __builtin_nontemporal_store(
        o, (f32x4*)(out + (size_t)(Rbase + r) * DD + l * 4));
  }
}

extern "C" void kernel_launch(void* const* d_in, const int* in_sizes, int n_in,
                              void* d_out, int out_size, void* d_ws, size_t ws_size,
                              hipStream_t stream) {
  const float* x = (const float*)d_in[0];
  const float* Wqkv = (const float*)d_in[1];
  const float* bqkv = (const float*)d_in[2];
  const float* Wout = (const float*)d_in[3];
  const float* bout = (const float*)d_in[4];
  float* out = (float*)d_out;

  __bf16* Wc = (__bf16*)d_ws;                                   // 128 KiB
  float* bc = (float*)((char*)d_ws + DD * DD * sizeof(__bf16)); // +1 KiB

  wc_bc_kernel<<<DD, 1024, 0, stream>>>(Wqkv, bqkv, Wout, bout, Wc, bc);
  knn_attn_main<<<NROWS / 32, 1024, 0, stream>>>(x, Wc, bc, out);
}